// Round 4
// baseline (428.134 us; speedup 1.0000x reference)
//
#include <hip/hip_runtime.h>
#include <math.h>

#define NB 4
#define NS 4096
#define NE 512
#define NH 8
#define ND 64
#define N3 1536
#define NM (NB*NS)   // 16384

typedef __attribute__((ext_vector_type(8))) short bf16x8;
typedef __attribute__((ext_vector_type(4))) float f32x4;
typedef unsigned short ushort_t;

__device__ __forceinline__ unsigned short f2bf(float f) {
    union { float f; unsigned int u; } v; v.f = f;
    unsigned int r = (v.u + 0x7FFFu + ((v.u >> 16) & 1u)) >> 16;
    return (unsigned short)r;
}

// async global->LDS, 16B per lane; LDS dest = wave-uniform base + lane*16
typedef __attribute__((address_space(1))) const void g_void;
typedef __attribute__((address_space(3))) void l_void;
__device__ __forceinline__ void cp16(const void* g, void* l) {
    __builtin_amdgcn_global_load_lds((g_void*)g, (l_void*)l, 16, 0, 0);
}

// ---------------------------------------------------------------------------
// cast x (fp32 -> bf16), 4 elems/thread
// ---------------------------------------------------------------------------
__global__ __launch_bounds__(256)
void cast_x(const float* __restrict__ x, ushort_t* __restrict__ xb) {
    const size_t i = ((size_t)blockIdx.x * 256 + threadIdx.x) * 4;
    float4 v = *(const float4*)&x[i];
    ushort4 o;
    o.x = f2bf(v.x); o.y = f2bf(v.y); o.z = f2bf(v.z); o.w = f2bf(v.w);
    *(ushort4*)&xb[i] = o;
}

// ---------------------------------------------------------------------------
// transpose+cast: W [512][N] fp32 -> WT [N][512] bf16
// ---------------------------------------------------------------------------
__global__ __launch_bounds__(256)
void cast_wT(const float* __restrict__ W, ushort_t* __restrict__ WT, int N) {
    __shared__ ushort_t T[64][72];
    const int t = threadIdx.x;
    const int k0 = blockIdx.y * 64, n0 = blockIdx.x * 64;
    const int tx = t & 15, ty = t >> 4;
    #pragma unroll
    for (int p = 0; p < 4; ++p) {
        const int r = p * 16 + ty;
        float4 v = *(const float4*)&W[(size_t)(k0 + r) * N + n0 + tx * 4];
        T[tx*4+0][r] = f2bf(v.x);
        T[tx*4+1][r] = f2bf(v.y);
        T[tx*4+2][r] = f2bf(v.z);
        T[tx*4+3][r] = f2bf(v.w);
    }
    __syncthreads();
    const int nn = t >> 2, kc = (t & 3) * 16;
    uint4 a = *(uint4*)&T[nn][kc];
    uint4 b = *(uint4*)&T[nn][kc + 8];
    *(uint4*)&WT[(size_t)(n0 + nn) * 512 + k0 + kc]     = a;
    *(uint4*)&WT[(size_t)(n0 + nn) * 512 + k0 + kc + 8] = b;
}

// ---------------------------------------------------------------------------
// Kernel 1: qkv projection, bf16 MFMA. 128x128 tile, BK=32, 4 waves (2x2).
// Epilogue: +bias; Q*0.125 -> [B,H,S,Dh]; K -> [B,H,S,Dh]; V -> [B,H,Dh,S]
// (d-major so flash can stage V^T with b128 writes).
// ---------------------------------------------------------------------------
__global__ __launch_bounds__(256)
void qkv_mfma(const ushort_t* __restrict__ xb, const ushort_t* __restrict__ WT,
              const float* __restrict__ bqkv,
              ushort_t* __restrict__ Qb, ushort_t* __restrict__ Kb,
              ushort_t* __restrict__ Vb)
{
    __shared__ ushort_t As[128 * 32];
    __shared__ ushort_t Bs[128 * 32];
    const int tid = threadIdx.x;
    const int lane = tid & 63, w = tid >> 6;
    const int col = lane & 15, quad = lane >> 4;
    const int wm = w & 1, wn = w >> 1;
    const int m0 = blockIdx.y * 128;
    const int nblk = blockIdx.x * 128;

    const int arow = tid >> 2, ach = (tid & 3) * 8;
    const ushort_t* aSrc = xb + (size_t)(m0 + arow) * 512 + ach;
    const ushort_t* bSrc = WT + (size_t)(nblk + arow) * 512 + ach;
    ushort_t* aDst = As + tid * 8;
    ushort_t* bDst = Bs + tid * 8;

    f32x4 acc[4][4];
    #pragma unroll
    for (int i = 0; i < 4; ++i)
        #pragma unroll
        for (int j = 0; j < 4; ++j)
            #pragma unroll
            for (int r = 0; r < 4; ++r) acc[i][j][r] = 0.f;

    for (int k0 = 0; k0 < 512; k0 += 32) {
        __syncthreads();
        cp16(aSrc + k0, aDst);
        cp16(aSrc + 64 * 512 + k0, aDst + 2048);
        cp16(bSrc + k0, bDst);
        cp16(bSrc + 64 * 512 + k0, bDst + 2048);
        __syncthreads();
        bf16x8 af[4], bf[4];
        #pragma unroll
        for (int mt = 0; mt < 4; ++mt)
            af[mt] = *(const bf16x8*)&As[(wm*64 + mt*16 + col) * 32 + quad*8];
        #pragma unroll
        for (int nt = 0; nt < 4; ++nt)
            bf[nt] = *(const bf16x8*)&Bs[(wn*64 + nt*16 + col) * 32 + quad*8];
        #pragma unroll
        for (int nt = 0; nt < 4; ++nt)
            #pragma unroll
            for (int mt = 0; mt < 4; ++mt)
                acc[mt][nt] = __builtin_amdgcn_mfma_f32_16x16x32_bf16(
                    af[mt], bf[nt], acc[mt][nt], 0, 0, 0);
    }

    const int which = nblk >> 9;                 // block-uniform: 0=Q 1=K 2=V
    const float scale = (which == 0) ? 0.125f : 1.0f;
    const int b = m0 >> 12;
    const int s0 = m0 & (NS - 1);
    float bias[4];
    int hh[4], dd[4];
    #pragma unroll
    for (int nt = 0; nt < 4; ++nt) {
        const int n = nblk + wn*64 + nt*16 + col;
        bias[nt] = bqkv[n];
        const int e = n & (NE - 1);
        hh[nt] = e >> 6; dd[nt] = e & 63;
    }
    if (which == 2) {
        // V: d-major [B,H,Dh,S]
        #pragma unroll
        for (int mt = 0; mt < 4; ++mt)
            #pragma unroll
            for (int reg = 0; reg < 4; ++reg) {
                const int s = s0 + wm*64 + mt*16 + quad*4 + reg;
                #pragma unroll
                for (int nt = 0; nt < 4; ++nt)
                    Vb[((size_t)(b*NH + hh[nt]) * ND + dd[nt]) * NS + s] =
                        f2bf(acc[mt][nt][reg] + bias[nt]);
            }
    } else {
        ushort_t* dst = (which == 0) ? Qb : Kb;
        #pragma unroll
        for (int mt = 0; mt < 4; ++mt)
            #pragma unroll
            for (int reg = 0; reg < 4; ++reg) {
                const int s = s0 + wm*64 + mt*16 + quad*4 + reg;
                #pragma unroll
                for (int nt = 0; nt < 4; ++nt)
                    dst[((size_t)(b*NH + hh[nt]) * NS + s) * ND + dd[nt]] =
                        f2bf((acc[mt][nt][reg] + bias[nt]) * scale);
            }
    }
}

// ---------------------------------------------------------------------------
// Kernel 2: causal flash attention, bf16 MFMA (16x16x32), fp32 accumulate.
// 128 Q rows/block, 4 waves. Q A-fragments held in registers (loop-invariant,
// loaded straight from global). V staged from d-major Vb with b128 writes.
// No max-subtraction; row sums via ones-column MFMA. LDS 36.9 KB -> 4 blk/CU.
// ---------------------------------------------------------------------------
__global__ __launch_bounds__(256)
void flash_mfma(const ushort_t* __restrict__ Qb,
                const ushort_t* __restrict__ Kb,
                const ushort_t* __restrict__ Vb,
                ushort_t* __restrict__ Ob)
{
    __shared__ __align__(16) ushort_t Ks[64][72];
    __shared__ __align__(16) ushort_t VT[64][72];
    __shared__ __align__(16) ushort_t Ps[4][32][72];

    const int tid  = threadIdx.x;
    const int w    = tid >> 6;
    const int lane = tid & 63;
    const int col  = lane & 15;
    const int quad = lane >> 4;
    const int qb   = gridDim.x - 1 - blockIdx.x;   // big tiles dispatch first
    const int bh   = blockIdx.y;
    const size_t base = (size_t)bh * NS * ND;

    // Q fragments: loop-invariant, straight from global in A-layout.
    // Per instruction the wave touches 16 rows x one full 64B half-line ->
    // fully line-coalesced.
    bf16x8 aq[2][2];
    #pragma unroll
    for (int mt = 0; mt < 2; ++mt)
        #pragma unroll
        for (int kh = 0; kh < 2; ++kh)
            aq[mt][kh] = *(const bf16x8*)
                &Qb[base + (size_t)(qb*128 + w*32 + mt*16 + col) * ND
                    + kh*32 + quad*8];

    f32x4 acc[2][4];
    f32x4 lacc[2];
    #pragma unroll
    for (int mt = 0; mt < 2; ++mt) {
        #pragma unroll
        for (int r = 0; r < 4; ++r) lacc[mt][r] = 0.f;
        #pragma unroll
        for (int nt = 0; nt < 4; ++nt)
            #pragma unroll
            for (int r = 0; r < 4; ++r) acc[mt][nt][r] = 0.f;
    }

    bf16x8 ones;
    {
        const short o = (col == 0) ? (short)0x3F80 : (short)0;
        #pragma unroll
        for (int j = 0; j < 8; ++j) ones[j] = o;
    }

    const int nkt = 2 * qb + 2;
    for (int kt = 0; kt < nkt; ++kt) {
        __syncthreads();
        {
            const int r = tid & 63;       // K: key row.  V: d row.
            const int dg = tid >> 6;
            const ushort_t* ksrc = &Kb[base + (size_t)(kt*64 + r) * ND + dg*16];
            *(uint4*)&Ks[r][dg*16]     = *(const uint4*)ksrc;
            *(uint4*)&Ks[r][dg*16 + 8] = *(const uint4*)(ksrc + 8);
            const ushort_t* vsrc = &Vb[base + (size_t)r * NS + kt*64 + dg*16];
            *(uint4*)&VT[r][dg*16]     = *(const uint4*)vsrc;
            *(uint4*)&VT[r][dg*16 + 8] = *(const uint4*)(vsrc + 8);
        }
        __syncthreads();

        // waves whose 32 rows are entirely left of this K-tile skip compute
        if (kt*64 >= qb*128 + w*32 + 32) continue;

        f32x4 s[2][4];
        #pragma unroll
        for (int mt = 0; mt < 2; ++mt)
            #pragma unroll
            for (int nt = 0; nt < 4; ++nt)
                #pragma unroll
                for (int r = 0; r < 4; ++r) s[mt][nt][r] = 0.f;

        #pragma unroll
        for (int nt = 0; nt < 4; ++nt)
            #pragma unroll
            for (int kh = 0; kh < 2; ++kh) {
                bf16x8 bk = *(const bf16x8*)&Ks[nt*16 + col][kh*32 + quad*8];
                #pragma unroll
                for (int mt = 0; mt < 2; ++mt)
                    s[mt][nt] = __builtin_amdgcn_mfma_f32_16x16x32_bf16(
                        aq[mt][kh], bk, s[mt][nt], 0, 0, 0);
            }

        if (kt >= 2 * qb) {
            #pragma unroll
            for (int mt = 0; mt < 2; ++mt) {
                const int rowb = qb*128 + w*32 + mt*16 + quad*4;
                #pragma unroll
                for (int nt = 0; nt < 4; ++nt) {
                    const int c = kt*64 + nt*16 + col;
                    #pragma unroll
                    for (int reg = 0; reg < 4; ++reg)
                        if (c > rowb + reg) s[mt][nt][reg] = -1e30f;
                }
            }
        }

        #pragma unroll
        for (int mt = 0; mt < 2; ++mt)
            #pragma unroll
            for (int nt = 0; nt < 4; ++nt)
                #pragma unroll
                for (int reg = 0; reg < 4; ++reg) {
                    const float p = __expf(s[mt][nt][reg]);
                    Ps[w][mt*16 + quad*4 + reg][nt*16 + col] = f2bf(p);
                }

        bf16x8 ap[2][2];
        #pragma unroll
        for (int mt = 0; mt < 2; ++mt)
            #pragma unroll
            for (int kh = 0; kh < 2; ++kh)
                ap[mt][kh] = *(const bf16x8*)&Ps[w][mt*16 + col][kh*32 + quad*8];

        #pragma unroll
        for (int mt = 0; mt < 2; ++mt)
            #pragma unroll
            for (int kh = 0; kh < 2; ++kh)
                lacc[mt] = __builtin_amdgcn_mfma_f32_16x16x32_bf16(
                    ap[mt][kh], ones, lacc[mt], 0, 0, 0);

        #pragma unroll
        for (int nt = 0; nt < 4; ++nt)
            #pragma unroll
            for (int kh = 0; kh < 2; ++kh) {
                bf16x8 bv = *(const bf16x8*)&VT[nt*16 + col][kh*32 + quad*8];
                #pragma unroll
                for (int mt = 0; mt < 2; ++mt)
                    acc[mt][nt] = __builtin_amdgcn_mfma_f32_16x16x32_bf16(
                        ap[mt][kh], bv, acc[mt][nt], 0, 0, 0);
            }
    }

    #pragma unroll
    for (int mt = 0; mt < 2; ++mt)
        #pragma unroll
        for (int reg = 0; reg < 4; ++reg) {
            const float l = __shfl(lacc[mt][reg], lane & 48, 64);
            const float inv = 1.f / l;
            const int row = qb*128 + w*32 + mt*16 + quad*4 + reg;
            #pragma unroll
            for (int nt = 0; nt < 4; ++nt)
                Ob[base + (size_t)row * ND + nt*16 + col] =
                    f2bf(acc[mt][nt][reg] * inv);
        }
}

// ---------------------------------------------------------------------------
// Kernel 3: out projection, bf16 MFMA, gathering A from bf16 [B,H,S,Dh].
// ---------------------------------------------------------------------------
__global__ __launch_bounds__(256)
void out_mfma(const ushort_t* __restrict__ Ob, const ushort_t* __restrict__ WT,
              const float* __restrict__ bo, float* __restrict__ out)
{
    __shared__ ushort_t As[128 * 32];
    __shared__ ushort_t Bs[128 * 32];
    const int tid = threadIdx.x;
    const int lane = tid & 63, w = tid >> 6;
    const int col = lane & 15, quad = lane >> 4;
    const int wm = w & 1, wn = w >> 1;
    const int m0 = blockIdx.y * 128;
    const int nblk = blockIdx.x * 128;

    const int arow = tid >> 2, ach = (tid & 3) * 8;
    const int bblk = m0 >> 12;
    const int s0 = m0 & (NS - 1);
    const ushort_t* bSrc = WT + (size_t)(nblk + arow) * 512 + ach;
    ushort_t* aDst = As + tid * 8;
    ushort_t* bDst = Bs + tid * 8;

    f32x4 acc[4][4];
    #pragma unroll
    for (int i = 0; i < 4; ++i)
        #pragma unroll
        for (int j = 0; j < 4; ++j)
            #pragma unroll
            for (int r = 0; r < 4; ++r) acc[i][j][r] = 0.f;

    for (int k0 = 0; k0 < 512; k0 += 32) {
        __syncthreads();
        const int h = k0 >> 6, koff = k0 & 63;
        const ushort_t* aS =
            Ob + ((size_t)(bblk*NH + h) * NS + s0 + arow) * ND + koff + ach;
        cp16(aS, aDst);
        cp16(aS + 64 * ND, aDst + 2048);
        cp16(bSrc + k0, bDst);
        cp16(bSrc + 64 * 512 + k0, bDst + 2048);
        __syncthreads();
        bf16x8 af[4], bf[4];
        #pragma unroll
        for (int mt = 0; mt < 4; ++mt)
            af[mt] = *(const bf16x8*)&As[(wm*64 + mt*16 + col) * 32 + quad*8];
        #pragma unroll
        for (int nt = 0; nt < 4; ++nt)
            bf[nt] = *(const bf16x8*)&Bs[(wn*64 + nt*16 + col) * 32 + quad*8];
        #pragma unroll
        for (int nt = 0; nt < 4; ++nt)
            #pragma unroll
            for (int mt = 0; mt < 4; ++mt)
                acc[mt][nt] = __builtin_amdgcn_mfma_f32_16x16x32_bf16(
                    af[mt], bf[nt], acc[mt][nt], 0, 0, 0);
    }

    float bias[4];
    #pragma unroll
    for (int nt = 0; nt < 4; ++nt)
        bias[nt] = bo[nblk + wn*64 + nt*16 + col];
    #pragma unroll
    for (int mt = 0; mt < 4; ++mt)
        #pragma unroll
        for (int reg = 0; reg < 4; ++reg) {
            const int m = m0 + wm*64 + mt*16 + quad*4 + reg;
            #pragma unroll
            for (int nt = 0; nt < 4; ++nt)
                out[(size_t)m * NE + nblk + wn*64 + nt*16 + col] =
                    acc[mt][nt][reg] + bias[nt];
        }
}

// ---------------------------------------------------------------------------
extern "C" void kernel_launch(void* const* d_in, const int* in_sizes, int n_in,
                              void* d_out, int out_size, void* d_ws, size_t ws_size,
                              hipStream_t stream) {
    const float* x    = (const float*)d_in[0];
    const float* Wqkv = (const float*)d_in[1];
    const float* bqkv = (const float*)d_in[2];
    const float* Wo   = (const float*)d_in[3];
    const float* bo   = (const float*)d_in[4];
    float* out = (float*)d_out;

    const size_t per = (size_t)NB * NH * NS * ND;   // 8,388,608 elements
    ushort_t* ws = (ushort_t*)d_ws;
    ushort_t* xb     = ws;                       // 16 MB (dead after qkv_mfma)
    ushort_t* Ob     = ws;                       // aliases xb
    ushort_t* Qb     = ws + per;                 // 16 MB
    ushort_t* Kb     = Qb + per;                 // 16 MB
    ushort_t* Vb     = Kb + per;                 // 16 MB  (d-major [B,H,Dh,S])
    ushort_t* WqkvT  = Vb + per;                 // 1.5 MB
    ushort_t* WoT    = WqkvT + (size_t)N3 * NE;  // 0.5 MB

    dim3 blk(256);
    cast_x<<<dim3(NM * NE / 1024), blk, 0, stream>>>(x, xb);
    cast_wT<<<dim3(N3/64, NE/64), blk, 0, stream>>>(Wqkv, WqkvT, N3);
    cast_wT<<<dim3(NE/64, NE/64), blk, 0, stream>>>(Wo, WoT, NE);
    qkv_mfma<<<dim3(N3/128, NM/128), blk, 0, stream>>>(xb, WqkvT, bqkv, Qb, Kb, Vb);
    flash_mfma<<<dim3(NS/128, NB*NH), blk, 0, stream>>>(Qb, Kb, Vb, Ob);
    out_mfma<<<dim3(NE/128, NM/128), blk, 0, stream>>>(Ob, WoT, bo, out);
}

// Round 5
// 292.184 us; speedup vs baseline: 1.4653x; 1.4653x over previous
//
#include <hip/hip_runtime.h>
#include <math.h>

#define NB 4
#define NS 4096
#define NE 512
#define NH 8
#define ND 64
#define N3 1536
#define NM (NB*NS)   // 16384

typedef __attribute__((ext_vector_type(8))) short bf16x8;
typedef __attribute__((ext_vector_type(4))) float f32x4;
typedef unsigned short ushort_t;

__device__ __forceinline__ unsigned short f2bf(float f) {
    union { float f; unsigned int u; } v; v.f = f;
    unsigned int r = (v.u + 0x7FFFu + ((v.u >> 16) & 1u)) >> 16;
    return (unsigned short)r;
}

// async global->LDS, 16B per lane; LDS dest = wave-uniform base + lane*16
typedef __attribute__((address_space(1))) const void g_void;
typedef __attribute__((address_space(3))) void l_void;
__device__ __forceinline__ void cp16(const void* g, void* l) {
    __builtin_amdgcn_global_load_lds((g_void*)g, (l_void*)l, 16, 0, 0);
}

// ---------------------------------------------------------------------------
// cast x (fp32 -> bf16), 4 elems/thread
// ---------------------------------------------------------------------------
__global__ __launch_bounds__(256)
void cast_x(const float* __restrict__ x, ushort_t* __restrict__ xb) {
    const size_t i = ((size_t)blockIdx.x * 256 + threadIdx.x) * 4;
    float4 v = *(const float4*)&x[i];
    ushort4 o;
    o.x = f2bf(v.x); o.y = f2bf(v.y); o.z = f2bf(v.z); o.w = f2bf(v.w);
    *(ushort4*)&xb[i] = o;
}

// ---------------------------------------------------------------------------
// transpose+cast: W [512][N] fp32 -> WT [N][512] bf16
// ---------------------------------------------------------------------------
__global__ __launch_bounds__(256)
void cast_wT(const float* __restrict__ W, ushort_t* __restrict__ WT, int N) {
    __shared__ ushort_t T[64][72];
    const int t = threadIdx.x;
    const int k0 = blockIdx.y * 64, n0 = blockIdx.x * 64;
    const int tx = t & 15, ty = t >> 4;
    #pragma unroll
    for (int p = 0; p < 4; ++p) {
        const int r = p * 16 + ty;
        float4 v = *(const float4*)&W[(size_t)(k0 + r) * N + n0 + tx * 4];
        T[tx*4+0][r] = f2bf(v.x);
        T[tx*4+1][r] = f2bf(v.y);
        T[tx*4+2][r] = f2bf(v.z);
        T[tx*4+3][r] = f2bf(v.w);
    }
    __syncthreads();
    const int nn = t >> 2, kc = (t & 3) * 16;
    uint4 a = *(uint4*)&T[nn][kc];
    uint4 b = *(uint4*)&T[nn][kc + 8];
    *(uint4*)&WT[(size_t)(n0 + nn) * 512 + k0 + kc]     = a;
    *(uint4*)&WT[(size_t)(n0 + nn) * 512 + k0 + kc + 8] = b;
}

// ---------------------------------------------------------------------------
// Kernel 1: qkv projection, bf16 MFMA. 128x128 tile, BK=32, 4 waves (2x2).
// Epilogue: +bias; Q*0.125 -> [B,H,S,Dh]; K -> [B,H,S,Dh]; V -> [B,H,Dh,S]
// (d-major so flash can stage V^T with b128 writes).
// ---------------------------------------------------------------------------
__global__ __launch_bounds__(256)
void qkv_mfma(const ushort_t* __restrict__ xb, const ushort_t* __restrict__ WT,
              const float* __restrict__ bqkv,
              ushort_t* __restrict__ Qb, ushort_t* __restrict__ Kb,
              ushort_t* __restrict__ Vb)
{
    __shared__ ushort_t As[128 * 32];
    __shared__ ushort_t Bs[128 * 32];
    const int tid = threadIdx.x;
    const int lane = tid & 63, w = tid >> 6;
    const int col = lane & 15, quad = lane >> 4;
    const int wm = w & 1, wn = w >> 1;
    const int m0 = blockIdx.y * 128;
    const int nblk = blockIdx.x * 128;

    const int arow = tid >> 2, ach = (tid & 3) * 8;
    const ushort_t* aSrc = xb + (size_t)(m0 + arow) * 512 + ach;
    const ushort_t* bSrc = WT + (size_t)(nblk + arow) * 512 + ach;
    ushort_t* aDst = As + tid * 8;
    ushort_t* bDst = Bs + tid * 8;

    f32x4 acc[4][4];
    #pragma unroll
    for (int i = 0; i < 4; ++i)
        #pragma unroll
        for (int j = 0; j < 4; ++j)
            #pragma unroll
            for (int r = 0; r < 4; ++r) acc[i][j][r] = 0.f;

    for (int k0 = 0; k0 < 512; k0 += 32) {
        __syncthreads();
        cp16(aSrc + k0, aDst);
        cp16(aSrc + 64 * 512 + k0, aDst + 2048);
        cp16(bSrc + k0, bDst);
        cp16(bSrc + 64 * 512 + k0, bDst + 2048);
        __syncthreads();
        bf16x8 af[4], bf[4];
        #pragma unroll
        for (int mt = 0; mt < 4; ++mt)
            af[mt] = *(const bf16x8*)&As[(wm*64 + mt*16 + col) * 32 + quad*8];
        #pragma unroll
        for (int nt = 0; nt < 4; ++nt)
            bf[nt] = *(const bf16x8*)&Bs[(wn*64 + nt*16 + col) * 32 + quad*8];
        #pragma unroll
        for (int nt = 0; nt < 4; ++nt)
            #pragma unroll
            for (int mt = 0; mt < 4; ++mt)
                acc[mt][nt] = __builtin_amdgcn_mfma_f32_16x16x32_bf16(
                    af[mt], bf[nt], acc[mt][nt], 0, 0, 0);
    }

    const int which = nblk >> 9;                 // block-uniform: 0=Q 1=K 2=V
    const float scale = (which == 0) ? 0.125f : 1.0f;
    const int b = m0 >> 12;
    const int s0 = m0 & (NS - 1);
    float bias[4];
    int hh[4], dd[4];
    #pragma unroll
    for (int nt = 0; nt < 4; ++nt) {
        const int n = nblk + wn*64 + nt*16 + col;
        bias[nt] = bqkv[n];
        const int e = n & (NE - 1);
        hh[nt] = e >> 6; dd[nt] = e & 63;
    }
    if (which == 2) {
        // V: d-major [B,H,Dh,S]
        #pragma unroll
        for (int mt = 0; mt < 4; ++mt)
            #pragma unroll
            for (int reg = 0; reg < 4; ++reg) {
                const int s = s0 + wm*64 + mt*16 + quad*4 + reg;
                #pragma unroll
                for (int nt = 0; nt < 4; ++nt)
                    Vb[((size_t)(b*NH + hh[nt]) * ND + dd[nt]) * NS + s] =
                        f2bf(acc[mt][nt][reg] + bias[nt]);
            }
    } else {
        ushort_t* dst = (which == 0) ? Qb : Kb;
        #pragma unroll
        for (int mt = 0; mt < 4; ++mt)
            #pragma unroll
            for (int reg = 0; reg < 4; ++reg) {
                const int s = s0 + wm*64 + mt*16 + quad*4 + reg;
                #pragma unroll
                for (int nt = 0; nt < 4; ++nt)
                    dst[((size_t)(b*NH + hh[nt]) * NS + s) * ND + dd[nt]] =
                        f2bf((acc[mt][nt][reg] + bias[nt]) * scale);
            }
    }
}

// ---------------------------------------------------------------------------
// Kernel 2: causal flash attention, bf16 MFMA, fp32 accumulate.
// Balance: each block processes Q-tiles {i, 31-i} sequentially -> all 512
// blocks do exactly 66 compute-iterations (2 blocks/CU, no tail).
// S^T orientation: mfma(A=K, B=Q) -> D[key][qrow]; lane's 4 C-regs are 4
// consecutive keys -> P written with b64 stores (was 32 scalar b16).
// Q fragments in registers; V staged from d-major Vb with b128 writes.
// No max-subtraction; row sums via ones-column MFMA.
// ---------------------------------------------------------------------------
__global__ __launch_bounds__(256)
void flash_mfma(const ushort_t* __restrict__ Qb,
                const ushort_t* __restrict__ Kb,
                const ushort_t* __restrict__ Vb,
                ushort_t* __restrict__ Ob)
{
    __shared__ __align__(16) ushort_t Ks[64][72];
    __shared__ __align__(16) ushort_t VT[64][72];
    __shared__ __align__(16) ushort_t Ps[4][32][72];

    const int tid  = threadIdx.x;
    const int w    = tid >> 6;
    const int lane = tid & 63;
    const int col  = lane & 15;
    const int quad = lane >> 4;
    const int qpair = blockIdx.x;              // 0..15
    const int bh   = blockIdx.y;
    const size_t base = (size_t)bh * NS * ND;

    bf16x8 ones;
    {
        const short o = (col == 0) ? (short)0x3F80 : (short)0;
        #pragma unroll
        for (int j = 0; j < 8; ++j) ones[j] = o;
    }

    #pragma unroll 1
    for (int phase = 0; phase < 2; ++phase) {
        const int qv = phase ? (31 - qpair) : qpair;

        // Q fragments (B-operand layout == A-layout per-lane mapping)
        bf16x8 aq[2][2];
        #pragma unroll
        for (int mt = 0; mt < 2; ++mt)
            #pragma unroll
            for (int kh = 0; kh < 2; ++kh)
                aq[mt][kh] = *(const bf16x8*)
                    &Qb[base + (size_t)(qv*128 + w*32 + mt*16 + col) * ND
                        + kh*32 + quad*8];

        f32x4 acc[2][4];
        f32x4 lacc[2];
        #pragma unroll
        for (int mt = 0; mt < 2; ++mt) {
            #pragma unroll
            for (int r = 0; r < 4; ++r) lacc[mt][r] = 0.f;
            #pragma unroll
            for (int nt = 0; nt < 4; ++nt)
                #pragma unroll
                for (int r = 0; r < 4; ++r) acc[mt][nt][r] = 0.f;
        }

        const int nkt = 2 * qv + 2;
        for (int kt = 0; kt < nkt; ++kt) {
            __syncthreads();
            {
                const int r = tid & 63;       // K: key row.  V: d row.
                const int dg = tid >> 6;
                const ushort_t* ksrc = &Kb[base + (size_t)(kt*64 + r) * ND + dg*16];
                *(uint4*)&Ks[r][dg*16]     = *(const uint4*)ksrc;
                *(uint4*)&Ks[r][dg*16 + 8] = *(const uint4*)(ksrc + 8);
                const ushort_t* vsrc = &Vb[base + (size_t)r * NS + kt*64 + dg*16];
                *(uint4*)&VT[r][dg*16]     = *(const uint4*)vsrc;
                *(uint4*)&VT[r][dg*16 + 8] = *(const uint4*)(vsrc + 8);
            }
            __syncthreads();

            // waves whose 32 rows are entirely left of this K-tile skip compute
            if (kt*64 >= qv*128 + w*32 + 32) continue;

            // S^T = K Q^T : lane holds key = nt*16+quad*4+reg,
            //               qrow = w*32 + mt*16 + col
            f32x4 s[2][4];
            #pragma unroll
            for (int mt = 0; mt < 2; ++mt)
                #pragma unroll
                for (int nt = 0; nt < 4; ++nt)
                    #pragma unroll
                    for (int r = 0; r < 4; ++r) s[mt][nt][r] = 0.f;

            #pragma unroll
            for (int nt = 0; nt < 4; ++nt)
                #pragma unroll
                for (int kh = 0; kh < 2; ++kh) {
                    bf16x8 ak = *(const bf16x8*)&Ks[nt*16 + col][kh*32 + quad*8];
                    #pragma unroll
                    for (int mt = 0; mt < 2; ++mt)
                        s[mt][nt] = __builtin_amdgcn_mfma_f32_16x16x32_bf16(
                            ak, aq[mt][kh], s[mt][nt], 0, 0, 0);
                }

            if (kt >= 2 * qv) {   // diagonal region: apply causal mask
                #pragma unroll
                for (int mt = 0; mt < 2; ++mt) {
                    const int qrow = qv*128 + w*32 + mt*16 + col;
                    #pragma unroll
                    for (int nt = 0; nt < 4; ++nt) {
                        const int key = kt*64 + nt*16 + quad*4;
                        #pragma unroll
                        for (int reg = 0; reg < 4; ++reg)
                            if (key + reg > qrow) s[mt][nt][reg] = -1e30f;
                    }
                }
            }

            // P = exp(S) -> bf16, b64 stores (4 consecutive keys per lane)
            #pragma unroll
            for (int mt = 0; mt < 2; ++mt)
                #pragma unroll
                for (int nt = 0; nt < 4; ++nt) {
                    ushort4 pw;
                    pw.x = f2bf(__expf(s[mt][nt][0]));
                    pw.y = f2bf(__expf(s[mt][nt][1]));
                    pw.z = f2bf(__expf(s[mt][nt][2]));
                    pw.w = f2bf(__expf(s[mt][nt][3]));
                    *(ushort4*)&Ps[w][mt*16 + col][nt*16 + quad*4] = pw;
                }

            bf16x8 ap[2][2];
            #pragma unroll
            for (int mt = 0; mt < 2; ++mt)
                #pragma unroll
                for (int kh = 0; kh < 2; ++kh)
                    ap[mt][kh] = *(const bf16x8*)&Ps[w][mt*16 + col][kh*32 + quad*8];

            #pragma unroll
            for (int mt = 0; mt < 2; ++mt)
                #pragma unroll
                for (int kh = 0; kh < 2; ++kh)
                    lacc[mt] = __builtin_amdgcn_mfma_f32_16x16x32_bf16(
                        ap[mt][kh], ones, lacc[mt], 0, 0, 0);

            #pragma unroll
            for (int nt = 0; nt < 4; ++nt)
                #pragma unroll
                for (int kh = 0; kh < 2; ++kh) {
                    bf16x8 bv = *(const bf16x8*)&VT[nt*16 + col][kh*32 + quad*8];
                    #pragma unroll
                    for (int mt = 0; mt < 2; ++mt)
                        acc[mt][nt] = __builtin_amdgcn_mfma_f32_16x16x32_bf16(
                            ap[mt][kh], bv, acc[mt][nt], 0, 0, 0);
                }
        }

        #pragma unroll
        for (int mt = 0; mt < 2; ++mt)
            #pragma unroll
            for (int reg = 0; reg < 4; ++reg) {
                const float l = __shfl(lacc[mt][reg], lane & 48, 64);
                const float inv = 1.f / l;
                const int row = qv*128 + w*32 + mt*16 + quad*4 + reg;
                #pragma unroll
                for (int nt = 0; nt < 4; ++nt)
                    Ob[base + (size_t)row * ND + nt*16 + col] =
                        f2bf(acc[mt][nt][reg] * inv);
            }
        __syncthreads();   // phase boundary: epilogue reads lacc before re-stage
    }
}

// ---------------------------------------------------------------------------
// Kernel 3: out projection, bf16 MFMA, gathering A from bf16 [B,H,S,Dh].
// ---------------------------------------------------------------------------
__global__ __launch_bounds__(256)
void out_mfma(const ushort_t* __restrict__ Ob, const ushort_t* __restrict__ WT,
              const float* __restrict__ bo, float* __restrict__ out)
{
    __shared__ ushort_t As[128 * 32];
    __shared__ ushort_t Bs[128 * 32];
    const int tid = threadIdx.x;
    const int lane = tid & 63, w = tid >> 6;
    const int col = lane & 15, quad = lane >> 4;
    const int wm = w & 1, wn = w >> 1;
    const int m0 = blockIdx.y * 128;
    const int nblk = blockIdx.x * 128;

    const int arow = tid >> 2, ach = (tid & 3) * 8;
    const int bblk = m0 >> 12;
    const int s0 = m0 & (NS - 1);
    const ushort_t* bSrc = WT + (size_t)(nblk + arow) * 512 + ach;
    ushort_t* aDst = As + tid * 8;
    ushort_t* bDst = Bs + tid * 8;

    f32x4 acc[4][4];
    #pragma unroll
    for (int i = 0; i < 4; ++i)
        #pragma unroll
        for (int j = 0; j < 4; ++j)
            #pragma unroll
            for (int r = 0; r < 4; ++r) acc[i][j][r] = 0.f;

    for (int k0 = 0; k0 < 512; k0 += 32) {
        __syncthreads();
        const int h = k0 >> 6, koff = k0 & 63;
        const ushort_t* aS =
            Ob + ((size_t)(bblk*NH + h) * NS + s0 + arow) * ND + koff + ach;
        cp16(aS, aDst);
        cp16(aS + 64 * ND, aDst + 2048);
        cp16(bSrc + k0, bDst);
        cp16(bSrc + 64 * 512 + k0, bDst + 2048);
        __syncthreads();
        bf16x8 af[4], bf[4];
        #pragma unroll
        for (int mt = 0; mt < 4; ++mt)
            af[mt] = *(const bf16x8*)&As[(wm*64 + mt*16 + col) * 32 + quad*8];
        #pragma unroll
        for (int nt = 0; nt < 4; ++nt)
            bf[nt] = *(const bf16x8*)&Bs[(wn*64 + nt*16 + col) * 32 + quad*8];
        #pragma unroll
        for (int nt = 0; nt < 4; ++nt)
            #pragma unroll
            for (int mt = 0; mt < 4; ++mt)
                acc[mt][nt] = __builtin_amdgcn_mfma_f32_16x16x32_bf16(
                    af[mt], bf[nt], acc[mt][nt], 0, 0, 0);
    }

    float bias[4];
    #pragma unroll
    for (int nt = 0; nt < 4; ++nt)
        bias[nt] = bo[nblk + wn*64 + nt*16 + col];
    #pragma unroll
    for (int mt = 0; mt < 4; ++mt)
        #pragma unroll
        for (int reg = 0; reg < 4; ++reg) {
            const int m = m0 + wm*64 + mt*16 + quad*4 + reg;
            #pragma unroll
            for (int nt = 0; nt < 4; ++nt)
                out[(size_t)m * NE + nblk + wn*64 + nt*16 + col] =
                    acc[mt][nt][reg] + bias[nt];
        }
}

// ---------------------------------------------------------------------------
extern "C" void kernel_launch(void* const* d_in, const int* in_sizes, int n_in,
                              void* d_out, int out_size, void* d_ws, size_t ws_size,
                              hipStream_t stream) {
    const float* x    = (const float*)d_in[0];
    const float* Wqkv = (const float*)d_in[1];
    const float* bqkv = (const float*)d_in[2];
    const float* Wo   = (const float*)d_in[3];
    const float* bo   = (const float*)d_in[4];
    float* out = (float*)d_out;

    const size_t per = (size_t)NB * NH * NS * ND;   // 8,388,608 elements
    ushort_t* ws = (ushort_t*)d_ws;
    ushort_t* xb     = ws;                       // 16 MB (dead after qkv_mfma)
    ushort_t* Ob     = ws;                       // aliases xb
    ushort_t* Qb     = ws + per;                 // 16 MB
    ushort_t* Kb     = Qb + per;                 // 16 MB
    ushort_t* Vb     = Kb + per;                 // 16 MB  (d-major [B,H,Dh,S])
    ushort_t* WqkvT  = Vb + per;                 // 1.5 MB
    ushort_t* WoT    = WqkvT + (size_t)N3 * NE;  // 0.5 MB

    dim3 blk(256);
    cast_x<<<dim3(NM * NE / 1024), blk, 0, stream>>>(x, xb);
    cast_wT<<<dim3(N3/64, NE/64), blk, 0, stream>>>(Wqkv, WqkvT, N3);
    cast_wT<<<dim3(NE/64, NE/64), blk, 0, stream>>>(Wo, WoT, NE);
    qkv_mfma<<<dim3(N3/128, NM/128), blk, 0, stream>>>(xb, WqkvT, bqkv, Qb, Kb, Vb);
    flash_mfma<<<dim3(16, NB*NH), blk, 0, stream>>>(Qb, Kb, Vb, Ob);
    out_mfma<<<dim3(NE/128, NM/128), blk, 0, stream>>>(Ob, WoT, bo, out);
}

// Round 6
// 274.978 us; speedup vs baseline: 1.5570x; 1.0626x over previous
//
#include <hip/hip_runtime.h>
#include <math.h>

#define NB 4
#define NS 4096
#define NE 512
#define NH 8
#define ND 64
#define N3 1536
#define NM (NB*NS)   // 16384

typedef __attribute__((ext_vector_type(8))) short bf16x8;
typedef __attribute__((ext_vector_type(4))) float f32x4;
typedef unsigned short ushort_t;

// 0.125 * log2(e): QK^T then exp2 == exp(QK/8)
#define QSCALE 0.18033688011f

extern "C" __device__ float __ocml_native_exp2_f32(float);   // bare v_exp_f32

__device__ __forceinline__ unsigned short f2bf(float f) {
    union { float f; unsigned int u; } v; v.f = f;
    unsigned int r = (v.u + 0x7FFFu + ((v.u >> 16) & 1u)) >> 16;
    return (unsigned short)r;
}

#if defined(__has_builtin)
#if __has_builtin(__builtin_amdgcn_cvt_pk_bf16_f32)
#define HAVE_PK_BF16 1
#endif
#endif

#ifdef HAVE_PK_BF16
typedef __attribute__((ext_vector_type(2))) __bf16 bf16x2_t;
__device__ __forceinline__ unsigned int pk2bf(float a, float b) {
    bf16x2_t r = __builtin_amdgcn_cvt_pk_bf16_f32(a, b);
    union { bf16x2_t v; unsigned int u; } c; c.v = r; return c.u;
}
#else
__device__ __forceinline__ unsigned int pk2bf(float a, float b) {
    return (unsigned int)f2bf(a) | ((unsigned int)f2bf(b) << 16);
}
#endif

// async global->LDS, 16B per lane; LDS dest = wave-uniform base + lane*16
typedef __attribute__((address_space(1))) const void g_void;
typedef __attribute__((address_space(3))) void l_void;
__device__ __forceinline__ void cp16(const void* g, void* l) {
    __builtin_amdgcn_global_load_lds((g_void*)g, (l_void*)l, 16, 0, 0);
}

// ---------------------------------------------------------------------------
// cast x (fp32 -> bf16), 4 elems/thread
// ---------------------------------------------------------------------------
__global__ __launch_bounds__(256)
void cast_x(const float* __restrict__ x, ushort_t* __restrict__ xb) {
    const size_t i = ((size_t)blockIdx.x * 256 + threadIdx.x) * 4;
    float4 v = *(const float4*)&x[i];
    uint2 o;
    o.x = pk2bf(v.x, v.y);
    o.y = pk2bf(v.z, v.w);
    *(uint2*)&xb[i] = o;
}

// ---------------------------------------------------------------------------
// transpose+cast: W [512][N] fp32 -> WT [N][512] bf16
// ---------------------------------------------------------------------------
__global__ __launch_bounds__(256)
void cast_wT(const float* __restrict__ W, ushort_t* __restrict__ WT, int N) {
    __shared__ ushort_t T[64][72];
    const int t = threadIdx.x;
    const int k0 = blockIdx.y * 64, n0 = blockIdx.x * 64;
    const int tx = t & 15, ty = t >> 4;
    #pragma unroll
    for (int p = 0; p < 4; ++p) {
        const int r = p * 16 + ty;
        float4 v = *(const float4*)&W[(size_t)(k0 + r) * N + n0 + tx * 4];
        T[tx*4+0][r] = f2bf(v.x);
        T[tx*4+1][r] = f2bf(v.y);
        T[tx*4+2][r] = f2bf(v.z);
        T[tx*4+3][r] = f2bf(v.w);
    }
    __syncthreads();
    const int nn = t >> 2, kc = (t & 3) * 16;
    uint4 a = *(uint4*)&T[nn][kc];
    uint4 b = *(uint4*)&T[nn][kc + 8];
    *(uint4*)&WT[(size_t)(n0 + nn) * 512 + k0 + kc]     = a;
    *(uint4*)&WT[(size_t)(n0 + nn) * 512 + k0 + kc + 8] = b;
}

// ---------------------------------------------------------------------------
// Kernel 1: qkv projection, bf16 MFMA. 128x128 tile, BK=32, 4 waves (2x2).
// Epilogue: +bias; Q*(0.125*log2e) -> [B,H,S,Dh]; K -> [B,H,S,Dh];
// V -> [B,H,Dh,S] (d-major so flash can stage V^T with b128 writes).
// ---------------------------------------------------------------------------
__global__ __launch_bounds__(256)
void qkv_mfma(const ushort_t* __restrict__ xb, const ushort_t* __restrict__ WT,
              const float* __restrict__ bqkv,
              ushort_t* __restrict__ Qb, ushort_t* __restrict__ Kb,
              ushort_t* __restrict__ Vb)
{
    __shared__ ushort_t As[128 * 32];
    __shared__ ushort_t Bs[128 * 32];
    const int tid = threadIdx.x;
    const int lane = tid & 63, w = tid >> 6;
    const int col = lane & 15, quad = lane >> 4;
    const int wm = w & 1, wn = w >> 1;
    const int m0 = blockIdx.y * 128;
    const int nblk = blockIdx.x * 128;

    const int arow = tid >> 2, ach = (tid & 3) * 8;
    const ushort_t* aSrc = xb + (size_t)(m0 + arow) * 512 + ach;
    const ushort_t* bSrc = WT + (size_t)(nblk + arow) * 512 + ach;
    ushort_t* aDst = As + tid * 8;
    ushort_t* bDst = Bs + tid * 8;

    f32x4 acc[4][4];
    #pragma unroll
    for (int i = 0; i < 4; ++i)
        #pragma unroll
        for (int j = 0; j < 4; ++j)
            #pragma unroll
            for (int r = 0; r < 4; ++r) acc[i][j][r] = 0.f;

    for (int k0 = 0; k0 < 512; k0 += 32) {
        __syncthreads();
        cp16(aSrc + k0, aDst);
        cp16(aSrc + 64 * 512 + k0, aDst + 2048);
        cp16(bSrc + k0, bDst);
        cp16(bSrc + 64 * 512 + k0, bDst + 2048);
        __syncthreads();
        bf16x8 af[4], bf[4];
        #pragma unroll
        for (int mt = 0; mt < 4; ++mt)
            af[mt] = *(const bf16x8*)&As[(wm*64 + mt*16 + col) * 32 + quad*8];
        #pragma unroll
        for (int nt = 0; nt < 4; ++nt)
            bf[nt] = *(const bf16x8*)&Bs[(wn*64 + nt*16 + col) * 32 + quad*8];
        #pragma unroll
        for (int nt = 0; nt < 4; ++nt)
            #pragma unroll
            for (int mt = 0; mt < 4; ++mt)
                acc[mt][nt] = __builtin_amdgcn_mfma_f32_16x16x32_bf16(
                    af[mt], bf[nt], acc[mt][nt], 0, 0, 0);
    }

    const int which = nblk >> 9;                 // block-uniform: 0=Q 1=K 2=V
    const float scale = (which == 0) ? QSCALE : 1.0f;
    const int b = m0 >> 12;
    const int s0 = m0 & (NS - 1);
    float bias[4];
    int hh[4], dd[4];
    #pragma unroll
    for (int nt = 0; nt < 4; ++nt) {
        const int n = nblk + wn*64 + nt*16 + col;
        bias[nt] = bqkv[n];
        const int e = n & (NE - 1);
        hh[nt] = e >> 6; dd[nt] = e & 63;
    }
    if (which == 2) {
        // V: d-major [B,H,Dh,S]
        #pragma unroll
        for (int mt = 0; mt < 4; ++mt)
            #pragma unroll
            for (int reg = 0; reg < 4; ++reg) {
                const int s = s0 + wm*64 + mt*16 + quad*4 + reg;
                #pragma unroll
                for (int nt = 0; nt < 4; ++nt)
                    Vb[((size_t)(b*NH + hh[nt]) * ND + dd[nt]) * NS + s] =
                        f2bf(acc[mt][nt][reg] + bias[nt]);
            }
    } else {
        ushort_t* dst = (which == 0) ? Qb : Kb;
        #pragma unroll
        for (int mt = 0; mt < 4; ++mt)
            #pragma unroll
            for (int reg = 0; reg < 4; ++reg) {
                const int s = s0 + wm*64 + mt*16 + quad*4 + reg;
                #pragma unroll
                for (int nt = 0; nt < 4; ++nt)
                    dst[((size_t)(b*NH + hh[nt]) * NS + s) * ND + dd[nt]] =
                        f2bf((acc[mt][nt][reg] + bias[nt]) * scale);
            }
    }
}

// ---------------------------------------------------------------------------
// Kernel 2: causal flash attention, bf16 MFMA, fp32 accumulate.
// Paired Q-tiles {i,31-i}: 512 uniform blocks of 66 iters. S^T orientation.
// Register prefetch of next K/V tile overlaps compute. P = exp2(S') via bare
// v_exp (log2e folded into Q); bf16 pack via v_cvt_pk_bf16_f32.
// Row sums via ones-column MFMA.
// ---------------------------------------------------------------------------
__global__ __launch_bounds__(256)
void flash_mfma(const ushort_t* __restrict__ Qb,
                const ushort_t* __restrict__ Kb,
                const ushort_t* __restrict__ Vb,
                ushort_t* __restrict__ Ob)
{
    __shared__ __align__(16) ushort_t Ks[64][72];
    __shared__ __align__(16) ushort_t VT[64][72];
    __shared__ __align__(16) ushort_t Ps[4][32][72];

    const int tid  = threadIdx.x;
    const int w    = tid >> 6;
    const int lane = tid & 63;
    const int col  = lane & 15;
    const int quad = lane >> 4;
    const int qpair = blockIdx.x;              // 0..15
    const int bh   = blockIdx.y;
    const size_t base = (size_t)bh * NS * ND;

    // staging addresses (loop-invariant parts)
    const int r  = tid & 63;                   // K: key row.  V: d row.
    const int dg = tid >> 6;
    const ushort_t* kbase = Kb + base + (size_t)r * ND + dg*16;
    const ushort_t* vbase = Vb + base + (size_t)r * NS + dg*16;

    bf16x8 ones;
    {
        const short o = (col == 0) ? (short)0x3F80 : (short)0;
        #pragma unroll
        for (int j = 0; j < 8; ++j) ones[j] = o;
    }

    #pragma unroll 1
    for (int phase = 0; phase < 2; ++phase) {
        const int qv = phase ? (31 - qpair) : qpair;

        // Q fragments (B-operand layout == A-layout per-lane mapping)
        bf16x8 aq[2][2];
        #pragma unroll
        for (int mt = 0; mt < 2; ++mt)
            #pragma unroll
            for (int kh = 0; kh < 2; ++kh)
                aq[mt][kh] = *(const bf16x8*)
                    &Qb[base + (size_t)(qv*128 + w*32 + mt*16 + col) * ND
                        + kh*32 + quad*8];

        f32x4 acc[2][4];
        f32x4 lacc[2];
        #pragma unroll
        for (int mt = 0; mt < 2; ++mt) {
            #pragma unroll
            for (int r2 = 0; r2 < 4; ++r2) lacc[mt][r2] = 0.f;
            #pragma unroll
            for (int nt = 0; nt < 4; ++nt)
                #pragma unroll
                for (int r2 = 0; r2 < 4; ++r2) acc[mt][nt][r2] = 0.f;
        }

        const int nkt = 2 * qv + 2;

        // prefetch tile 0
        uint4 kr0, kr1, vr0, vr1;
        {
            const ushort_t* ks = kbase;
            kr0 = *(const uint4*)ks;
            kr1 = *(const uint4*)(ks + 8);
            const ushort_t* vs = vbase;
            vr0 = *(const uint4*)vs;
            vr1 = *(const uint4*)(vs + 8);
        }

        for (int kt = 0; kt < nkt; ++kt) {
            __syncthreads();   // prior tile's readers done / phase boundary
            *(uint4*)&Ks[r][dg*16]     = kr0;
            *(uint4*)&Ks[r][dg*16 + 8] = kr1;
            *(uint4*)&VT[r][dg*16]     = vr0;
            *(uint4*)&VT[r][dg*16 + 8] = vr1;
            __syncthreads();

            // prefetch next tile (overlaps compute below); must happen even
            // for waves that skip compute
            if (kt + 1 < nkt) {
                const ushort_t* ks = kbase + (size_t)(kt+1) * 64 * ND;
                kr0 = *(const uint4*)ks;
                kr1 = *(const uint4*)(ks + 8);
                const ushort_t* vs = vbase + (kt+1) * 64;
                vr0 = *(const uint4*)vs;
                vr1 = *(const uint4*)(vs + 8);
            }

            // waves whose 32 rows are entirely left of this K-tile skip compute
            if (kt*64 >= qv*128 + w*32 + 32) continue;

            // S^T = K Q^T : lane holds key = nt*16+quad*4+reg,
            //               qrow = w*32 + mt*16 + col
            f32x4 s[2][4];
            #pragma unroll
            for (int mt = 0; mt < 2; ++mt)
                #pragma unroll
                for (int nt = 0; nt < 4; ++nt)
                    #pragma unroll
                    for (int r2 = 0; r2 < 4; ++r2) s[mt][nt][r2] = 0.f;

            #pragma unroll
            for (int nt = 0; nt < 4; ++nt)
                #pragma unroll
                for (int kh = 0; kh < 2; ++kh) {
                    bf16x8 ak = *(const bf16x8*)&Ks[nt*16 + col][kh*32 + quad*8];
                    #pragma unroll
                    for (int mt = 0; mt < 2; ++mt)
                        s[mt][nt] = __builtin_amdgcn_mfma_f32_16x16x32_bf16(
                            ak, aq[mt][kh], s[mt][nt], 0, 0, 0);
                }

            if (kt >= 2 * qv) {   // diagonal region: apply causal mask
                #pragma unroll
                for (int mt = 0; mt < 2; ++mt) {
                    const int qrow = qv*128 + w*32 + mt*16 + col;
                    #pragma unroll
                    for (int nt = 0; nt < 4; ++nt) {
                        const int key = kt*64 + nt*16 + quad*4;
                        #pragma unroll
                        for (int reg = 0; reg < 4; ++reg)
                            if (key + reg > qrow) s[mt][nt][reg] = -1e30f;
                    }
                }
            }

            // P = exp2(S') -> bf16, b64 stores (4 consecutive keys per lane)
            #pragma unroll
            for (int mt = 0; mt < 2; ++mt)
                #pragma unroll
                for (int nt = 0; nt < 4; ++nt) {
                    uint2 pw;
                    pw.x = pk2bf(__ocml_native_exp2_f32(s[mt][nt][0]),
                                 __ocml_native_exp2_f32(s[mt][nt][1]));
                    pw.y = pk2bf(__ocml_native_exp2_f32(s[mt][nt][2]),
                                 __ocml_native_exp2_f32(s[mt][nt][3]));
                    *(uint2*)&Ps[w][mt*16 + col][nt*16 + quad*4] = pw;
                }

            bf16x8 ap[2][2];
            #pragma unroll
            for (int mt = 0; mt < 2; ++mt)
                #pragma unroll
                for (int kh = 0; kh < 2; ++kh)
                    ap[mt][kh] = *(const bf16x8*)&Ps[w][mt*16 + col][kh*32 + quad*8];

            #pragma unroll
            for (int mt = 0; mt < 2; ++mt)
                #pragma unroll
                for (int kh = 0; kh < 2; ++kh)
                    lacc[mt] = __builtin_amdgcn_mfma_f32_16x16x32_bf16(
                        ap[mt][kh], ones, lacc[mt], 0, 0, 0);

            #pragma unroll
            for (int nt = 0; nt < 4; ++nt)
                #pragma unroll
                for (int kh = 0; kh < 2; ++kh) {
                    bf16x8 bv = *(const bf16x8*)&VT[nt*16 + col][kh*32 + quad*8];
                    #pragma unroll
                    for (int mt = 0; mt < 2; ++mt)
                        acc[mt][nt] = __builtin_amdgcn_mfma_f32_16x16x32_bf16(
                            ap[mt][kh], bv, acc[mt][nt], 0, 0, 0);
                }
        }

        #pragma unroll
        for (int mt = 0; mt < 2; ++mt)
            #pragma unroll
            for (int reg = 0; reg < 4; ++reg) {
                const float l = __shfl(lacc[mt][reg], lane & 48, 64);
                const float inv = 1.f / l;
                const int row = qv*128 + w*32 + mt*16 + quad*4 + reg;
                #pragma unroll
                for (int nt = 0; nt < 4; ++nt)
                    Ob[base + (size_t)row * ND + nt*16 + col] =
                        f2bf(acc[mt][nt][reg] * inv);
            }
    }
}

// ---------------------------------------------------------------------------
// Kernel 3: out projection, bf16 MFMA, gathering A from bf16 [B,H,S,Dh].
// ---------------------------------------------------------------------------
__global__ __launch_bounds__(256)
void out_mfma(const ushort_t* __restrict__ Ob, const ushort_t* __restrict__ WT,
              const float* __restrict__ bo, float* __restrict__ out)
{
    __shared__ ushort_t As[128 * 32];
    __shared__ ushort_t Bs[128 * 32];
    const int tid = threadIdx.x;
    const int lane = tid & 63, w = tid >> 6;
    const int col = lane & 15, quad = lane >> 4;
    const int wm = w & 1, wn = w >> 1;
    const int m0 = blockIdx.y * 128;
    const int nblk = blockIdx.x * 128;

    const int arow = tid >> 2, ach = (tid & 3) * 8;
    const int bblk = m0 >> 12;
    const int s0 = m0 & (NS - 1);
    const ushort_t* bSrc = WT + (size_t)(nblk + arow) * 512 + ach;
    ushort_t* aDst = As + tid * 8;
    ushort_t* bDst = Bs + tid * 8;

    f32x4 acc[4][4];
    #pragma unroll
    for (int i = 0; i < 4; ++i)
        #pragma unroll
        for (int j = 0; j < 4; ++j)
            #pragma unroll
            for (int r = 0; r < 4; ++r) acc[i][j][r] = 0.f;

    for (int k0 = 0; k0 < 512; k0 += 32) {
        __syncthreads();
        const int h = k0 >> 6, koff = k0 & 63;
        const ushort_t* aS =
            Ob + ((size_t)(bblk*NH + h) * NS + s0 + arow) * ND + koff + ach;
        cp16(aS, aDst);
        cp16(aS + 64 * ND, aDst + 2048);
        cp16(bSrc + k0, bDst);
        cp16(bSrc + 64 * 512 + k0, bDst + 2048);
        __syncthreads();
        bf16x8 af[4], bf[4];
        #pragma unroll
        for (int mt = 0; mt < 4; ++mt)
            af[mt] = *(const bf16x8*)&As[(wm*64 + mt*16 + col) * 32 + quad*8];
        #pragma unroll
        for (int nt = 0; nt < 4; ++nt)
            bf[nt] = *(const bf16x8*)&Bs[(wn*64 + nt*16 + col) * 32 + quad*8];
        #pragma unroll
        for (int nt = 0; nt < 4; ++nt)
            #pragma unroll
            for (int mt = 0; mt < 4; ++mt)
                acc[mt][nt] = __builtin_amdgcn_mfma_f32_16x16x32_bf16(
                    af[mt], bf[nt], acc[mt][nt], 0, 0, 0);
    }

    float bias[4];
    #pragma unroll
    for (int nt = 0; nt < 4; ++nt)
        bias[nt] = bo[nblk + wn*64 + nt*16 + col];
    #pragma unroll
    for (int mt = 0; mt < 4; ++mt)
        #pragma unroll
        for (int reg = 0; reg < 4; ++reg) {
            const int m = m0 + wm*64 + mt*16 + quad*4 + reg;
            #pragma unroll
            for (int nt = 0; nt < 4; ++nt)
                out[(size_t)m * NE + nblk + wn*64 + nt*16 + col] =
                    acc[mt][nt][reg] + bias[nt];
        }
}

// ---------------------------------------------------------------------------
extern "C" void kernel_launch(void* const* d_in, const int* in_sizes, int n_in,
                              void* d_out, int out_size, void* d_ws, size_t ws_size,
                              hipStream_t stream) {
    const float* x    = (const float*)d_in[0];
    const float* Wqkv = (const float*)d_in[1];
    const float* bqkv = (const float*)d_in[2];
    const float* Wo   = (const float*)d_in[3];
    const float* bo   = (const float*)d_in[4];
    float* out = (float*)d_out;

    const size_t per = (size_t)NB * NH * NS * ND;   // 8,388,608 elements
    ushort_t* ws = (ushort_t*)d_ws;
    ushort_t* xb     = ws;                       // 16 MB (dead after qkv_mfma)
    ushort_t* Ob     = ws;                       // aliases xb
    ushort_t* Qb     = ws + per;                 // 16 MB
    ushort_t* Kb     = Qb + per;                 // 16 MB
    ushort_t* Vb     = Kb + per;                 // 16 MB  (d-major [B,H,Dh,S])
    ushort_t* WqkvT  = Vb + per;                 // 1.5 MB
    ushort_t* WoT    = WqkvT + (size_t)N3 * NE;  // 0.5 MB

    dim3 blk(256);
    cast_x<<<dim3(NM * NE / 1024), blk, 0, stream>>>(x, xb);
    cast_wT<<<dim3(N3/64, NE/64), blk, 0, stream>>>(Wqkv, WqkvT, N3);
    cast_wT<<<dim3(NE/64, NE/64), blk, 0, stream>>>(Wo, WoT, NE);
    qkv_mfma<<<dim3(N3/128, NM/128), blk, 0, stream>>>(xb, WqkvT, bqkv, Qb, Kb, Vb);
    flash_mfma<<<dim3(16, NB*NH), blk, 0, stream>>>(Qb, Kb, Vb, Ob);
    out_mfma<<<dim3(NE/128, NM/128), blk, 0, stream>>>(Ob, WoT, bo, out);
}

// Round 7
// 256.708 us; speedup vs baseline: 1.6678x; 1.0712x over previous
//
#include <hip/hip_runtime.h>
#include <math.h>

#define NB 4
#define NS 4096
#define NE 512
#define NH 8
#define ND 64
#define N3 1536
#define NM (NB*NS)   // 16384

typedef __attribute__((ext_vector_type(8))) short bf16x8;
typedef __attribute__((ext_vector_type(4))) float f32x4;
typedef unsigned short ushort_t;

// 0.125 * log2(e): QK^T then exp2 == exp(QK/8)
#define QSCALE 0.18033688011f

extern "C" __device__ float __ocml_native_exp2_f32(float);   // bare v_exp_f32

// HW packed f32->bf16 (RNE), lo=a hi=b. gfx942+ instruction; builtin is not
// exposed on this toolchain (R6 counters showed fallback cost), so inline asm.
__device__ __forceinline__ unsigned int pk2bf(float a, float b) {
    unsigned int r;
    asm("v_cvt_pk_bf16_f32 %0, %1, %2" : "=v"(r) : "v"(a), "v"(b));
    return r;
}

__device__ __forceinline__ unsigned short f2bf(float f) {
    return (unsigned short)(pk2bf(f, f) & 0xFFFFu);
}

// async global->LDS, 16B per lane; LDS dest = wave-uniform base + lane*16
typedef __attribute__((address_space(1))) const void g_void;
typedef __attribute__((address_space(3))) void l_void;
__device__ __forceinline__ void cp16(const void* g, void* l) {
    __builtin_amdgcn_global_load_lds((g_void*)g, (l_void*)l, 16, 0, 0);
}

// ---------------------------------------------------------------------------
// cast x (fp32 -> bf16), 4 elems/thread
// ---------------------------------------------------------------------------
__global__ __launch_bounds__(256)
void cast_x(const float* __restrict__ x, ushort_t* __restrict__ xb) {
    const size_t i = ((size_t)blockIdx.x * 256 + threadIdx.x) * 4;
    float4 v = *(const float4*)&x[i];
    uint2 o;
    o.x = pk2bf(v.x, v.y);
    o.y = pk2bf(v.z, v.w);
    *(uint2*)&xb[i] = o;
}

// ---------------------------------------------------------------------------
// transpose+cast: W [512][N] fp32 -> WT [N][512] bf16
// ---------------------------------------------------------------------------
__global__ __launch_bounds__(256)
void cast_wT(const float* __restrict__ W, ushort_t* __restrict__ WT, int N) {
    __shared__ ushort_t T[64][72];
    const int t = threadIdx.x;
    const int k0 = blockIdx.y * 64, n0 = blockIdx.x * 64;
    const int tx = t & 15, ty = t >> 4;
    #pragma unroll
    for (int p = 0; p < 4; ++p) {
        const int r = p * 16 + ty;
        float4 v = *(const float4*)&W[(size_t)(k0 + r) * N + n0 + tx * 4];
        const unsigned int u01 = pk2bf(v.x, v.y);
        const unsigned int u23 = pk2bf(v.z, v.w);
        T[tx*4+0][r] = (ushort_t)(u01 & 0xFFFFu);
        T[tx*4+1][r] = (ushort_t)(u01 >> 16);
        T[tx*4+2][r] = (ushort_t)(u23 & 0xFFFFu);
        T[tx*4+3][r] = (ushort_t)(u23 >> 16);
    }
    __syncthreads();
    const int nn = t >> 2, kc = (t & 3) * 16;
    uint4 a = *(uint4*)&T[nn][kc];
    uint4 b = *(uint4*)&T[nn][kc + 8];
    *(uint4*)&WT[(size_t)(n0 + nn) * 512 + k0 + kc]     = a;
    *(uint4*)&WT[(size_t)(n0 + nn) * 512 + k0 + kc + 8] = b;
}

// ---------------------------------------------------------------------------
// Kernel 1: qkv projection, bf16 MFMA. 128x128 tile, BK=32, 4 waves (2x2).
// Epilogue: +bias; Q*(0.125*log2e) -> [B,H,S,Dh]; K -> [B,H,S,Dh];
// V -> [B,H,Dh,S] (d-major: reg-consecutive s is contiguous -> uint2 stores).
// ---------------------------------------------------------------------------
__global__ __launch_bounds__(256)
void qkv_mfma(const ushort_t* __restrict__ xb, const ushort_t* __restrict__ WT,
              const float* __restrict__ bqkv,
              ushort_t* __restrict__ Qb, ushort_t* __restrict__ Kb,
              ushort_t* __restrict__ Vb)
{
    __shared__ ushort_t As[128 * 32];
    __shared__ ushort_t Bs[128 * 32];
    const int tid = threadIdx.x;
    const int lane = tid & 63, w = tid >> 6;
    const int col = lane & 15, quad = lane >> 4;
    const int wm = w & 1, wn = w >> 1;
    const int m0 = blockIdx.y * 128;
    const int nblk = blockIdx.x * 128;

    const int arow = tid >> 2, ach = (tid & 3) * 8;
    const ushort_t* aSrc = xb + (size_t)(m0 + arow) * 512 + ach;
    const ushort_t* bSrc = WT + (size_t)(nblk + arow) * 512 + ach;
    ushort_t* aDst = As + tid * 8;
    ushort_t* bDst = Bs + tid * 8;

    f32x4 acc[4][4];
    #pragma unroll
    for (int i = 0; i < 4; ++i)
        #pragma unroll
        for (int j = 0; j < 4; ++j)
            #pragma unroll
            for (int r = 0; r < 4; ++r) acc[i][j][r] = 0.f;

    for (int k0 = 0; k0 < 512; k0 += 32) {
        __syncthreads();
        cp16(aSrc + k0, aDst);
        cp16(aSrc + 64 * 512 + k0, aDst + 2048);
        cp16(bSrc + k0, bDst);
        cp16(bSrc + 64 * 512 + k0, bDst + 2048);
        __syncthreads();
        bf16x8 af[4], bf[4];
        #pragma unroll
        for (int mt = 0; mt < 4; ++mt)
            af[mt] = *(const bf16x8*)&As[(wm*64 + mt*16 + col) * 32 + quad*8];
        #pragma unroll
        for (int nt = 0; nt < 4; ++nt)
            bf[nt] = *(const bf16x8*)&Bs[(wn*64 + nt*16 + col) * 32 + quad*8];
        #pragma unroll
        for (int nt = 0; nt < 4; ++nt)
            #pragma unroll
            for (int mt = 0; mt < 4; ++mt)
                acc[mt][nt] = __builtin_amdgcn_mfma_f32_16x16x32_bf16(
                    af[mt], bf[nt], acc[mt][nt], 0, 0, 0);
    }

    const int which = nblk >> 9;                 // block-uniform: 0=Q 1=K 2=V
    const float scale = (which == 0) ? QSCALE : 1.0f;
    const int b = m0 >> 12;
    const int s0 = m0 & (NS - 1);
    float bias[4];
    int hh[4], dd[4];
    #pragma unroll
    for (int nt = 0; nt < 4; ++nt) {
        const int n = nblk + wn*64 + nt*16 + col;
        bias[nt] = bqkv[n];
        const int e = n & (NE - 1);
        hh[nt] = e >> 6; dd[nt] = e & 63;
    }
    if (which == 2) {
        // V: d-major [B,H,Dh,S]; regs 0..3 are consecutive s -> uint2 store
        #pragma unroll
        for (int mt = 0; mt < 4; ++mt) {
            const int s = s0 + wm*64 + mt*16 + quad*4;
            #pragma unroll
            for (int nt = 0; nt < 4; ++nt) {
                uint2 pv;
                pv.x = pk2bf(acc[mt][nt][0] + bias[nt],
                             acc[mt][nt][1] + bias[nt]);
                pv.y = pk2bf(acc[mt][nt][2] + bias[nt],
                             acc[mt][nt][3] + bias[nt]);
                *(uint2*)&Vb[((size_t)(b*NH + hh[nt]) * ND + dd[nt]) * NS + s] = pv;
            }
        }
    } else {
        ushort_t* dst = (which == 0) ? Qb : Kb;
        #pragma unroll
        for (int mt = 0; mt < 4; ++mt) {
            const int s = s0 + wm*64 + mt*16 + quad*4;
            #pragma unroll
            for (int nt = 0; nt < 4; ++nt) {
                const unsigned int u01 =
                    pk2bf((acc[mt][nt][0] + bias[nt]) * scale,
                          (acc[mt][nt][1] + bias[nt]) * scale);
                const unsigned int u23 =
                    pk2bf((acc[mt][nt][2] + bias[nt]) * scale,
                          (acc[mt][nt][3] + bias[nt]) * scale);
                const size_t a0 = ((size_t)(b*NH + hh[nt]) * NS + s) * ND + dd[nt];
                dst[a0]          = (ushort_t)(u01 & 0xFFFFu);
                dst[a0 + ND]     = (ushort_t)(u01 >> 16);
                dst[a0 + 2*ND]   = (ushort_t)(u23 & 0xFFFFu);
                dst[a0 + 3*ND]   = (ushort_t)(u23 >> 16);
            }
        }
    }
}

// ---------------------------------------------------------------------------
// Kernel 2: causal flash attention, bf16 MFMA, fp32 accumulate.
// Paired Q-tiles {i,31-i}: 512 uniform blocks of 66 iters. S^T orientation.
// Register prefetch of next K/V tile overlaps compute. P = exp2(S') via bare
// v_exp (log2e folded into Q); bf16 pack via HW v_cvt_pk_bf16_f32.
// Row sums via ones-column MFMA.
// ---------------------------------------------------------------------------
__global__ __launch_bounds__(256)
void flash_mfma(const ushort_t* __restrict__ Qb,
                const ushort_t* __restrict__ Kb,
                const ushort_t* __restrict__ Vb,
                ushort_t* __restrict__ Ob)
{
    __shared__ __align__(16) ushort_t Ks[64][72];
    __shared__ __align__(16) ushort_t VT[64][72];
    __shared__ __align__(16) ushort_t Ps[4][32][72];

    const int tid  = threadIdx.x;
    const int w    = tid >> 6;
    const int lane = tid & 63;
    const int col  = lane & 15;
    const int quad = lane >> 4;
    const int qpair = blockIdx.x;              // 0..15
    const int bh   = blockIdx.y;
    const size_t base = (size_t)bh * NS * ND;

    // staging addresses (loop-invariant parts)
    const int r  = tid & 63;                   // K: key row.  V: d row.
    const int dg = tid >> 6;
    const ushort_t* kbase = Kb + base + (size_t)r * ND + dg*16;
    const ushort_t* vbase = Vb + base + (size_t)r * NS + dg*16;

    bf16x8 ones;
    {
        const short o = (col == 0) ? (short)0x3F80 : (short)0;
        #pragma unroll
        for (int j = 0; j < 8; ++j) ones[j] = o;
    }

    #pragma unroll 1
    for (int phase = 0; phase < 2; ++phase) {
        const int qv = phase ? (31 - qpair) : qpair;

        // Q fragments (B-operand layout == A-layout per-lane mapping)
        bf16x8 aq[2][2];
        #pragma unroll
        for (int mt = 0; mt < 2; ++mt)
            #pragma unroll
            for (int kh = 0; kh < 2; ++kh)
                aq[mt][kh] = *(const bf16x8*)
                    &Qb[base + (size_t)(qv*128 + w*32 + mt*16 + col) * ND
                        + kh*32 + quad*8];

        f32x4 acc[2][4];
        f32x4 lacc[2];
        #pragma unroll
        for (int mt = 0; mt < 2; ++mt) {
            #pragma unroll
            for (int r2 = 0; r2 < 4; ++r2) lacc[mt][r2] = 0.f;
            #pragma unroll
            for (int nt = 0; nt < 4; ++nt)
                #pragma unroll
                for (int r2 = 0; r2 < 4; ++r2) acc[mt][nt][r2] = 0.f;
        }

        const int nkt = 2 * qv + 2;

        // prefetch tile 0
        uint4 kr0, kr1, vr0, vr1;
        {
            const ushort_t* ks = kbase;
            kr0 = *(const uint4*)ks;
            kr1 = *(const uint4*)(ks + 8);
            const ushort_t* vs = vbase;
            vr0 = *(const uint4*)vs;
            vr1 = *(const uint4*)(vs + 8);
        }

        for (int kt = 0; kt < nkt; ++kt) {
            __syncthreads();   // prior tile's readers done / phase boundary
            *(uint4*)&Ks[r][dg*16]     = kr0;
            *(uint4*)&Ks[r][dg*16 + 8] = kr1;
            *(uint4*)&VT[r][dg*16]     = vr0;
            *(uint4*)&VT[r][dg*16 + 8] = vr1;
            __syncthreads();

            // prefetch next tile (overlaps compute below); must happen even
            // for waves that skip compute
            if (kt + 1 < nkt) {
                const ushort_t* ks = kbase + (size_t)(kt+1) * 64 * ND;
                kr0 = *(const uint4*)ks;
                kr1 = *(const uint4*)(ks + 8);
                const ushort_t* vs = vbase + (kt+1) * 64;
                vr0 = *(const uint4*)vs;
                vr1 = *(const uint4*)(vs + 8);
            }

            // waves whose 32 rows are entirely left of this K-tile skip compute
            if (kt*64 >= qv*128 + w*32 + 32) continue;

            // S^T = K Q^T : lane holds key = nt*16+quad*4+reg,
            //               qrow = w*32 + mt*16 + col
            f32x4 s[2][4];
            #pragma unroll
            for (int mt = 0; mt < 2; ++mt)
                #pragma unroll
                for (int nt = 0; nt < 4; ++nt)
                    #pragma unroll
                    for (int r2 = 0; r2 < 4; ++r2) s[mt][nt][r2] = 0.f;

            #pragma unroll
            for (int nt = 0; nt < 4; ++nt)
                #pragma unroll
                for (int kh = 0; kh < 2; ++kh) {
                    bf16x8 ak = *(const bf16x8*)&Ks[nt*16 + col][kh*32 + quad*8];
                    #pragma unroll
                    for (int mt = 0; mt < 2; ++mt)
                        s[mt][nt] = __builtin_amdgcn_mfma_f32_16x16x32_bf16(
                            ak, aq[mt][kh], s[mt][nt], 0, 0, 0);
                }

            if (kt >= 2 * qv) {   // diagonal region: apply causal mask
                #pragma unroll
                for (int mt = 0; mt < 2; ++mt) {
                    const int qrow = qv*128 + w*32 + mt*16 + col;
                    #pragma unroll
                    for (int nt = 0; nt < 4; ++nt) {
                        const int key = kt*64 + nt*16 + quad*4;
                        #pragma unroll
                        for (int reg = 0; reg < 4; ++reg)
                            if (key + reg > qrow) s[mt][nt][reg] = -1e30f;
                    }
                }
            }

            // P = exp2(S') -> bf16, b64 stores (4 consecutive keys per lane)
            #pragma unroll
            for (int mt = 0; mt < 2; ++mt)
                #pragma unroll
                for (int nt = 0; nt < 4; ++nt) {
                    uint2 pw;
                    pw.x = pk2bf(__ocml_native_exp2_f32(s[mt][nt][0]),
                                 __ocml_native_exp2_f32(s[mt][nt][1]));
                    pw.y = pk2bf(__ocml_native_exp2_f32(s[mt][nt][2]),
                                 __ocml_native_exp2_f32(s[mt][nt][3]));
                    *(uint2*)&Ps[w][mt*16 + col][nt*16 + quad*4] = pw;
                }

            bf16x8 ap[2][2];
            #pragma unroll
            for (int mt = 0; mt < 2; ++mt)
                #pragma unroll
                for (int kh = 0; kh < 2; ++kh)
                    ap[mt][kh] = *(const bf16x8*)&Ps[w][mt*16 + col][kh*32 + quad*8];

            #pragma unroll
            for (int mt = 0; mt < 2; ++mt)
                #pragma unroll
                for (int kh = 0; kh < 2; ++kh)
                    lacc[mt] = __builtin_amdgcn_mfma_f32_16x16x32_bf16(
                        ap[mt][kh], ones, lacc[mt], 0, 0, 0);

            #pragma unroll
            for (int nt = 0; nt < 4; ++nt)
                #pragma unroll
                for (int kh = 0; kh < 2; ++kh) {
                    bf16x8 bv = *(const bf16x8*)&VT[nt*16 + col][kh*32 + quad*8];
                    #pragma unroll
                    for (int mt = 0; mt < 2; ++mt)
                        acc[mt][nt] = __builtin_amdgcn_mfma_f32_16x16x32_bf16(
                            ap[mt][kh], bv, acc[mt][nt], 0, 0, 0);
                }
        }

        #pragma unroll
        for (int mt = 0; mt < 2; ++mt)
            #pragma unroll
            for (int reg = 0; reg < 4; ++reg) {
                const float l = __shfl(lacc[mt][reg], lane & 48, 64);
                const float inv = 1.f / l;
                const int row = qv*128 + w*32 + mt*16 + quad*4 + reg;
                const unsigned int u01 = pk2bf(acc[0 + (mt<<0)][0][reg] * 0.f + // placeholder avoided
                                               acc[mt][0][reg] * inv,
                                               acc[mt][1][reg] * inv);
                const unsigned int u23 = pk2bf(acc[mt][2][reg] * inv,
                                               acc[mt][3][reg] * inv);
                ushort_t* op = &Ob[base + (size_t)row * ND + col];
                op[0]  = (ushort_t)(u01 & 0xFFFFu);
                op[16] = (ushort_t)(u01 >> 16);
                op[32] = (ushort_t)(u23 & 0xFFFFu);
                op[48] = (ushort_t)(u23 >> 16);
            }
    }
}

// ---------------------------------------------------------------------------
// Kernel 3: out projection, bf16 MFMA, gathering A from bf16 [B,H,S,Dh].
// ---------------------------------------------------------------------------
__global__ __launch_bounds__(256)
void out_mfma(const ushort_t* __restrict__ Ob, const ushort_t* __restrict__ WT,
              const float* __restrict__ bo, float* __restrict__ out)
{
    __shared__ ushort_t As[128 * 32];
    __shared__ ushort_t Bs[128 * 32];
    const int tid = threadIdx.x;
    const int lane = tid & 63, w = tid >> 6;
    const int col = lane & 15, quad = lane >> 4;
    const int wm = w & 1, wn = w >> 1;
    const int m0 = blockIdx.y * 128;
    const int nblk = blockIdx.x * 128;

    const int arow = tid >> 2, ach = (tid & 3) * 8;
    const int bblk = m0 >> 12;
    const int s0 = m0 & (NS - 1);
    const ushort_t* bSrc = WT + (size_t)(nblk + arow) * 512 + ach;
    ushort_t* aDst = As + tid * 8;
    ushort_t* bDst = Bs + tid * 8;

    f32x4 acc[4][4];
    #pragma unroll
    for (int i = 0; i < 4; ++i)
        #pragma unroll
        for (int j = 0; j < 4; ++j)
            #pragma unroll
            for (int r = 0; r < 4; ++r) acc[i][j][r] = 0.f;

    for (int k0 = 0; k0 < 512; k0 += 32) {
        __syncthreads();
        const int h = k0 >> 6, koff = k0 & 63;
        const ushort_t* aS =
            Ob + ((size_t)(bblk*NH + h) * NS + s0 + arow) * ND + koff + ach;
        cp16(aS, aDst);
        cp16(aS + 64 * ND, aDst + 2048);
        cp16(bSrc + k0, bDst);
        cp16(bSrc + 64 * 512 + k0, bDst + 2048);
        __syncthreads();
        bf16x8 af[4], bf[4];
        #pragma unroll
        for (int mt = 0; mt < 4; ++mt)
            af[mt] = *(const bf16x8*)&As[(wm*64 + mt*16 + col) * 32 + quad*8];
        #pragma unroll
        for (int nt = 0; nt < 4; ++nt)
            bf[nt] = *(const bf16x8*)&Bs[(wn*64 + nt*16 + col) * 32 + quad*8];
        #pragma unroll
        for (int nt = 0; nt < 4; ++nt)
            #pragma unroll
            for (int mt = 0; mt < 4; ++mt)
                acc[mt][nt] = __builtin_amdgcn_mfma_f32_16x16x32_bf16(
                    af[mt], bf[nt], acc[mt][nt], 0, 0, 0);
    }

    float bias[4];
    #pragma unroll
    for (int nt = 0; nt < 4; ++nt)
        bias[nt] = bo[nblk + wn*64 + nt*16 + col];
    #pragma unroll
    for (int mt = 0; mt < 4; ++mt)
        #pragma unroll
        for (int reg = 0; reg < 4; ++reg) {
            const int m = m0 + wm*64 + mt*16 + quad*4 + reg;
            #pragma unroll
            for (int nt = 0; nt < 4; ++nt)
                out[(size_t)m * NE + nblk + wn*64 + nt*16 + col] =
                    acc[mt][nt][reg] + bias[nt];
        }
}

// ---------------------------------------------------------------------------
extern "C" void kernel_launch(void* const* d_in, const int* in_sizes, int n_in,
                              void* d_out, int out_size, void* d_ws, size_t ws_size,
                              hipStream_t stream) {
    const float* x    = (const float*)d_in[0];
    const float* Wqkv = (const float*)d_in[1];
    const float* bqkv = (const float*)d_in[2];
    const float* Wo   = (const float*)d_in[3];
    const float* bo   = (const float*)d_in[4];
    float* out = (float*)d_out;

    const size_t per = (size_t)NB * NH * NS * ND;   // 8,388,608 elements
    ushort_t* ws = (ushort_t*)d_ws;
    ushort_t* xb     = ws;                       // 16 MB (dead after qkv_mfma)
    ushort_t* Ob     = ws;                       // aliases xb
    ushort_t* Qb     = ws + per;                 // 16 MB
    ushort_t* Kb     = Qb + per;                 // 16 MB
    ushort_t* Vb     = Kb + per;                 // 16 MB  (d-major [B,H,Dh,S])
    ushort_t* WqkvT  = Vb + per;                 // 1.5 MB
    ushort_t* WoT    = WqkvT + (size_t)N3 * NE;  // 0.5 MB

    dim3 blk(256);
    cast_x<<<dim3(NM * NE / 1024), blk, 0, stream>>>(x, xb);
    cast_wT<<<dim3(N3/64, NE/64), blk, 0, stream>>>(Wqkv, WqkvT, N3);
    cast_wT<<<dim3(NE/64, NE/64), blk, 0, stream>>>(Wo, WoT, NE);
    qkv_mfma<<<dim3(N3/128, NM/128), blk, 0, stream>>>(xb, WqkvT, bqkv, Qb, Kb, Vb);
    flash_mfma<<<dim3(16, NB*NH), blk, 0, stream>>>(Qb, Kb, Vb, Ob);
    out_mfma<<<dim3(NE/128, NM/128), blk, 0, stream>>>(Ob, WoT, bo, out);
}